// Round 2
// baseline (149.234 us; speedup 1.0000x reference)
//
#include <hip/hip_runtime.h>

// Conv2D 3x3 stride-1 pad-1, C_IN=C_OUT=16, H=W=1024, fp32 in/out.
// Two-kernel implicit-GEMM:
//   k1: fp32 NCHW -> bf16 [1026][1026][16] (1-px zero border) in d_ws
//   k2: stage halo tile via global_load_lds (async DMA), mfma_f32_16x16x32_bf16
// k2 LDS layout [row][col][cin16] (32B/pixel) == global x' layout, so the
// whole 38016B tile is lane-contiguous chunks for global_load_lds.

#define HH 1024
#define WW 1024
#define CIN 16
#define COUT 16
#define TW 64
#define TH 16
#define LROWS (TH + 2)
#define LCOLS (TW + 2)
#define PIX 16           // shorts per pixel (32B)
#define XPW 1026         // x' width/height with border

typedef short v8s __attribute__((ext_vector_type(8)));
typedef float v4f __attribute__((ext_vector_type(4)));
typedef unsigned int u32;

__device__ __forceinline__ unsigned short f32_bf16(float f) {
    union { float f; u32 u; } v;
    v.f = f;
    u32 u = v.u;
    u += 0x7fffu + ((u >> 16) & 1u);  // RNE
    return (unsigned short)(u >> 16);
}

// ---------------- kernel 1: pack/convert/border ----------------
__global__ __launch_bounds__(256)
void conv_pack(const float* __restrict__ x, unsigned short* __restrict__ xp) {
    const int hp = blockIdx.x;      // 0..1025
    const int h = hp - 1;
    if ((unsigned)h >= (unsigned)HH) {
        // zero whole border row: 1026*16 shorts = 2052 uint4
        uint4 z = {0u, 0u, 0u, 0u};
        uint4* dst = (uint4*)(xp + (size_t)hp * XPW * PIX);
        for (int i = threadIdx.x; i < XPW * 2; i += 256) dst[i] = z;
        return;
    }
    // zero left/right border pixels of this row (2 uint4 each)
    if (threadIdx.x < 4) {
        uint4 z = {0u, 0u, 0u, 0u};
        if (threadIdx.x < 2) {
            uint4* d0 = (uint4*)(xp + (size_t)hp * XPW * PIX);
            d0[threadIdx.x] = z;
        } else {
            uint4* d1 = (uint4*)(xp + ((size_t)hp * XPW + 1025) * PIX);
            d1[threadIdx.x - 2] = z;
        }
    }
    const int t = threadIdx.x;
    for (int wbase = 0; wbase < WW; wbase += 512) {
        const int w = wbase + 2 * t;          // 2 pixels per thread
        const float* src = x + (size_t)h * WW + w;
        u32 p0[8], p1[8];
        #pragma unroll
        for (int c = 0; c < CIN; c += 2) {
            float2 va = *(const float2*)(src + (size_t)c * HH * WW);
            float2 vb = *(const float2*)(src + (size_t)(c + 1) * HH * WW);
            // pixel0 holds cin c,c+1 in one u32; pixel1 likewise
            p0[c >> 1] = (u32)f32_bf16(va.x) | ((u32)f32_bf16(vb.x) << 16);
            p1[c >> 1] = (u32)f32_bf16(va.y) | ((u32)f32_bf16(vb.y) << 16);
        }
        uint4* dst = (uint4*)(xp + ((size_t)hp * XPW + (w + 1)) * PIX);
        dst[0] = *(uint4*)&p0[0];
        dst[1] = *(uint4*)&p0[4];
        dst[2] = *(uint4*)&p1[0];
        dst[3] = *(uint4*)&p1[4];
    }
}

// wait: pixel layout must be cin-fastest per pixel. p0 u32 j holds cin 2j,2j+1 -> 8 u32 = 1 pixel. OK.

// ---------------- kernel 2: conv via MFMA ----------------
typedef const __attribute__((address_space(1))) u32* gptr_t;
typedef __attribute__((address_space(3))) u32* lptr_t;

__global__ __launch_bounds__(256, 4)
void conv3x3_mfma(const unsigned short* __restrict__ xp,
                  const float* __restrict__ wgt,
                  const float* __restrict__ bias,
                  float* __restrict__ out) {
    __shared__ __align__(16) unsigned short sm[LROWS * LCOLS * PIX];  // 38016 B

    const int tid = threadIdx.x;
    const int lane = tid & 63;
    const int wave = tid >> 6;
    const int h0 = blockIdx.y * TH;
    const int w0 = blockIdx.x * TW;

    // ---- stage 38016B = 2376 x 16B chunks via global_load_lds ----
    // chunk cid -> LDS bytes [cid*16, +16); row r = cid/132, in-row o = cid%132
    const unsigned char* xpb = (const unsigned char*)xp;
    #pragma unroll
    for (int it = 0; it < 10; ++it) {
        int cid = it * 256 + wave * 64 + lane;
        if (cid < (LROWS * LCOLS * PIX * 2) / 16) {   // 2376
            int r = cid / 132;
            int o = cid - r * 132;
            const unsigned char* g =
                xpb + ((size_t)(h0 + r) * XPW + w0) * (PIX * 2) + (size_t)o * 16;
            lptr_t l = (lptr_t)((__attribute__((address_space(3))) unsigned char*)sm +
                                (it * 256 + wave * 64) * 16);
            __builtin_amdgcn_global_load_lds((gptr_t)g, l, 16, 0, 0);
        }
    }

    const int m = lane & 15;       // c_out row of A / pixel index n in B&D
    const int q = lane >> 4;       // quad
    const int qh = q >> 1;         // kh in MFMA #1 (0 or 1)
    const int qc = (q & 1) * 8;    // cin offset in MFMA #1

    // ---- A fragments (weights) ----
    v8s a1[3], a2[3];
    for (int kw = 0; kw < 3; ++kw) {
        for (int j = 0; j < 8; ++j) {
            a1[kw][j] = (short)f32_bf16(wgt[((m * CIN + (qc + j)) * 3 + qh) * 3 + kw]);
            short t2 = 0;
            if (q < 2)
                t2 = (short)f32_bf16(wgt[((m * CIN + (q * 8 + j)) * 3 + 2) * 3 + kw]);
            a2[kw][j] = t2;
        }
    }
    float bl[4];
    #pragma unroll
    for (int i = 0; i < 4; ++i) bl[i] = bias[q * 4 + i];

    __syncthreads();   // drains vmcnt (incl. global_load_lds) + barrier

    // ---- compute: wave = 16-pixel column group, loop TH rows ----
    const int colbase = wave * 16 + m;
    for (int r = 0; r < TH; ++r) {
        v4f accA = {0.f, 0.f, 0.f, 0.f};
        v4f accB = {0.f, 0.f, 0.f, 0.f};
        #pragma unroll
        for (int kw = 0; kw < 3; ++kw) {
            const int col = colbase + kw;
            v8s b1 = *(const v8s*)&sm[((r + qh) * LCOLS + col) * PIX + qc];
            accA = __builtin_amdgcn_mfma_f32_16x16x32_bf16(a1[kw], b1, accA, 0, 0, 0);
            v8s b2 = {0, 0, 0, 0, 0, 0, 0, 0};
            if (q < 2)
                b2 = *(const v8s*)&sm[((r + 2) * LCOLS + col) * PIX + q * 8];
            accB = __builtin_amdgcn_mfma_f32_16x16x32_bf16(a2[kw], b2, accB, 0, 0, 0);
        }
        const int h = h0 + r;
        float* op = out + (size_t)h * WW + (w0 + colbase);
        #pragma unroll
        for (int i = 0; i < 4; ++i)
            op[(size_t)(q * 4 + i) * (HH * WW)] = accA[i] + accB[i] + bl[i];
    }
}

// ---------------- fallback (round-1 kernel, used if ws too small) ----------------
__global__ __launch_bounds__(256, 4)
void conv3x3_mfma_fb(const float* __restrict__ x,
                     const float* __restrict__ wgt,
                     const float* __restrict__ bias,
                     float* __restrict__ out) {
    __shared__ __align__(16) unsigned short sm[LROWS * LCOLS * PIX];
    const int tid = threadIdx.x;
    const int h0 = blockIdx.y * TH;
    const int w0 = blockIdx.x * TW;
    const int E = LROWS * LCOLS * CIN;
    for (int e = tid; e < E; e += 256) {
        int c = e % LCOLS;
        int t = e / LCOLS;
        int r = t % LROWS;
        int cin = t / LROWS;
        int gh = h0 - 1 + r;
        int gw = w0 - 1 + c;
        float v = 0.0f;
        if ((unsigned)gh < (unsigned)HH && (unsigned)gw < (unsigned)WW)
            v = x[cin * (HH * WW) + gh * WW + gw];
        sm[(r * LCOLS + c) * PIX + cin] = f32_bf16(v);
    }
    const int lane = tid & 63;
    const int wave = tid >> 6;
    const int m = lane & 15;
    const int q = lane >> 4;
    const int qh = q >> 1;
    const int qc = (q & 1) * 8;
    v8s a1[3], a2[3];
    for (int kw = 0; kw < 3; ++kw) {
        for (int j = 0; j < 8; ++j) {
            a1[kw][j] = (short)f32_bf16(wgt[((m * CIN + (qc + j)) * 3 + qh) * 3 + kw]);
            short t2 = 0;
            if (q < 2)
                t2 = (short)f32_bf16(wgt[((m * CIN + (q * 8 + j)) * 3 + 2) * 3 + kw]);
            a2[kw][j] = t2;
        }
    }
    float bl[4];
    #pragma unroll
    for (int i = 0; i < 4; ++i) bl[i] = bias[q * 4 + i];
    __syncthreads();
    const int colbase = wave * 16 + m;
    for (int r = 0; r < TH; ++r) {
        v4f accA = {0.f, 0.f, 0.f, 0.f};
        v4f accB = {0.f, 0.f, 0.f, 0.f};
        #pragma unroll
        for (int kw = 0; kw < 3; ++kw) {
            const int col = colbase + kw;
            v8s b1 = *(const v8s*)&sm[((r + qh) * LCOLS + col) * PIX + qc];
            accA = __builtin_amdgcn_mfma_f32_16x16x32_bf16(a1[kw], b1, accA, 0, 0, 0);
            v8s b2 = {0, 0, 0, 0, 0, 0, 0, 0};
            if (q < 2)
                b2 = *(const v8s*)&sm[((r + 2) * LCOLS + col) * PIX + q * 8];
            accB = __builtin_amdgcn_mfma_f32_16x16x32_bf16(a2[kw], b2, accB, 0, 0, 0);
        }
        const int h = h0 + r;
        float* op = out + h * WW + (w0 + colbase);
        #pragma unroll
        for (int i = 0; i < 4; ++i)
            op[(q * 4 + i) * (HH * WW)] = accA[i] + accB[i] + bl[i];
    }
}

extern "C" void kernel_launch(void* const* d_in, const int* in_sizes, int n_in,
                              void* d_out, int out_size, void* d_ws, size_t ws_size,
                              hipStream_t stream) {
    const float* x = (const float*)d_in[0];
    const float* w = (const float*)d_in[1];
    const float* b = (const float*)d_in[2];
    float* out = (float*)d_out;
    const size_t need = (size_t)XPW * XPW * PIX * sizeof(unsigned short);  // ~33.7MB
    if (ws_size >= need) {
        unsigned short* xp = (unsigned short*)d_ws;
        conv_pack<<<dim3(XPW), dim3(256), 0, stream>>>(x, xp);
        dim3 grid(WW / TW, HH / TH);
        conv3x3_mfma<<<grid, dim3(256), 0, stream>>>(xp, w, b, out);
    } else {
        dim3 grid(WW / TW, HH / TH);
        conv3x3_mfma_fb<<<grid, dim3(256), 0, stream>>>(x, w, b, out);
    }
}

// Round 3
// 145.075 us; speedup vs baseline: 1.0287x; 1.0287x over previous
//
#include <hip/hip_runtime.h>

// Conv2D 3x3 stride-1 pad-1, C_IN=C_OUT=16, H=W=1024, fp32 in/out.
// Two-kernel implicit-GEMM:
//   k1 (pack): fp32 NCHW -> bf16 [1026][1026][16] (1-px zero border) in d_ws
//   k2 (conv): stage 18x66 halo tile via global_load_lds (async DMA) with a
//              16B-chunk XOR swizzle (kills the 4-way ds_read_b128 bank
//              conflict from the 32B/pixel stride), then 5 full K=32 MFMAs
//              per output row: 18 k-chunks = 9 (kh,kw) x 2 cin-halves,
//              chunk t=4g+q on MFMA g / lane-quad q.

#define HH 1024
#define WW 1024
#define CIN 16
#define COUT 16
#define TW 64
#define TH 16
#define LROWS (TH + 2)
#define LCOLS (TW + 2)
#define PIX 16           // shorts per pixel (32B)
#define XPW 1026         // x' width/height with border
#define NCHUNK (LROWS * LCOLS * 2)   // 16B chunks per tile = 2376

typedef short v8s __attribute__((ext_vector_type(8)));
typedef float v4f __attribute__((ext_vector_type(4)));
typedef unsigned int u32;

__device__ __forceinline__ unsigned short f32_bf16(float f) {
    union { float f; u32 u; } v;
    v.f = f;
    u32 u = v.u;
    u += 0x7fffu + ((u >> 16) & 1u);  // RNE
    return (unsigned short)(u >> 16);
}

// ---------------- kernel 1: pack/convert/border ----------------
__global__ __launch_bounds__(256)
void conv_pack(const float* __restrict__ x, unsigned short* __restrict__ xp) {
    const int hp = blockIdx.x;      // 0..1025
    const int h = hp - 1;
    if ((unsigned)h >= (unsigned)HH) {
        uint4 z = {0u, 0u, 0u, 0u};
        uint4* dst = (uint4*)(xp + (size_t)hp * XPW * PIX);
        for (int i = threadIdx.x; i < XPW * 2; i += 256) dst[i] = z;
        return;
    }
    if (threadIdx.x < 4) {
        uint4 z = {0u, 0u, 0u, 0u};
        if (threadIdx.x < 2) {
            uint4* d0 = (uint4*)(xp + (size_t)hp * XPW * PIX);
            d0[threadIdx.x] = z;
        } else {
            uint4* d1 = (uint4*)(xp + ((size_t)hp * XPW + 1025) * PIX);
            d1[threadIdx.x - 2] = z;
        }
    }
    const int t = threadIdx.x;
    for (int wbase = 0; wbase < WW; wbase += 512) {
        const int w = wbase + 2 * t;          // 2 pixels per thread
        const float* src = x + (size_t)h * WW + w;
        u32 p0[8], p1[8];
        #pragma unroll
        for (int c = 0; c < CIN; c += 2) {
            float2 va = *(const float2*)(src + (size_t)c * HH * WW);
            float2 vb = *(const float2*)(src + (size_t)(c + 1) * HH * WW);
            p0[c >> 1] = (u32)f32_bf16(va.x) | ((u32)f32_bf16(vb.x) << 16);
            p1[c >> 1] = (u32)f32_bf16(va.y) | ((u32)f32_bf16(vb.y) << 16);
        }
        uint4* dst = (uint4*)(xp + ((size_t)hp * XPW + (w + 1)) * PIX);
        dst[0] = *(uint4*)&p0[0];
        dst[1] = *(uint4*)&p0[4];
        dst[2] = *(uint4*)&p1[0];
        dst[3] = *(uint4*)&p1[4];
    }
}

// ---------------- kernel 2: conv via MFMA ----------------
typedef const __attribute__((address_space(1))) u32* gptr_t;
typedef __attribute__((address_space(3))) u32* lptr_t;

__global__ __launch_bounds__(256, 4)
void conv3x3_mfma(const unsigned short* __restrict__ xp,
                  const float* __restrict__ wgt,
                  const float* __restrict__ bias,
                  float* __restrict__ out) {
    __shared__ __align__(16) unsigned short sm[LROWS * LCOLS * PIX];  // 38016 B

    const int tid = threadIdx.x;
    const int lane = tid & 63;
    const int wave = tid >> 6;
    const int h0 = blockIdx.y * TH;
    const int w0 = blockIdx.x * TW;

    // ---- stage tile via global_load_lds; physical chunk P = swizzle(logical L)
    // swizzle: phys = c ^ ((c>>3)&1)  (involution within each 8-chunk group).
    // DMA dest is lane-contiguous physical chunks; we permute the SOURCE:
    // lane holding physical P fetches logical L = P ^ ((P>>3)&1).
    const unsigned char* xpb = (const unsigned char*)xp;
    #pragma unroll
    for (int it = 0; it < 10; ++it) {
        int P = it * 256 + wave * 64 + lane;
        if (P < NCHUNK) {
            int L = P ^ ((P >> 3) & 1);
            int r = L / 132;               // chunks per LDS row = 66*2
            int o = L - r * 132;
            const unsigned char* g =
                xpb + ((size_t)(h0 + r) * XPW + w0) * (PIX * 2) + (size_t)o * 16;
            lptr_t l = (lptr_t)((__attribute__((address_space(3))) unsigned char*)sm +
                                (it * 256 + wave * 64) * 16);
            __builtin_amdgcn_global_load_lds((gptr_t)g, l, 16, 0, 0);
        }
    }

    const int m = lane & 15;       // c_out row of A == pixel index n of B/D
    const int q = lane >> 4;       // quad: supplies k = 8q..8q+7 of each MFMA
    const int colbase = wave * 16 + m;

    // ---- K packing: chunk t = 4g+q, t=0..17 -> (kh,kw,half); t>=18 dead ----
    v8s a[5];
    int Kofs[5];
    #pragma unroll
    for (int g5 = 0; g5 < 5; ++g5) {
        int t = 4 * g5 + q;
        int tt = t > 17 ? 17 : t;      // dead lanes read a harmless valid addr
        int khkw = tt >> 1;
        int kh = khkw / 3;
        int kw = khkw - 3 * kh;
        int half = tt & 1;
        Kofs[g5] = (kh * LCOLS + colbase + kw) * 2 + half;   // logical chunk, row term added later
        bool valid = t < 18;
        #pragma unroll
        for (int j = 0; j < 8; ++j) {
            float wv = valid ? wgt[((m * CIN + half * 8 + j) * 3 + kh) * 3 + kw] : 0.0f;
            a[g5][j] = (short)f32_bf16(wv);
        }
    }
    float bl[4];
    #pragma unroll
    for (int i = 0; i < 4; ++i) bl[i] = bias[q * 4 + i];

    __syncthreads();   // drains vmcnt (incl. global_load_lds) + barrier

    // ---- compute: wave = 16-pixel column group, loop TH rows ----
    #pragma unroll 4
    for (int r = 0; r < TH; ++r) {
        v4f acc = {0.f, 0.f, 0.f, 0.f};
        #pragma unroll
        for (int g5 = 0; g5 < 5; ++g5) {
            int c = r * 132 + Kofs[g5];          // logical chunk
            int phys = c ^ ((c >> 3) & 1);       // swizzled physical chunk
            v8s b = *(const v8s*)(sm + phys * 8);
            acc = __builtin_amdgcn_mfma_f32_16x16x32_bf16(a[g5], b, acc, 0, 0, 0);
        }
        float* op = out + (size_t)(h0 + r) * WW + (w0 + colbase);
        #pragma unroll
        for (int i = 0; i < 4; ++i)
            op[(size_t)(q * 4 + i) * (HH * WW)] = acc[i] + bl[i];
    }
}

// ---------------- fallback (round-1 kernel, used if ws too small) ----------------
__global__ __launch_bounds__(256, 4)
void conv3x3_mfma_fb(const float* __restrict__ x,
                     const float* __restrict__ wgt,
                     const float* __restrict__ bias,
                     float* __restrict__ out) {
    __shared__ __align__(16) unsigned short sm[LROWS * LCOLS * PIX];
    const int tid = threadIdx.x;
    const int h0 = blockIdx.y * TH;
    const int w0 = blockIdx.x * TW;
    const int E = LROWS * LCOLS * CIN;
    for (int e = tid; e < E; e += 256) {
        int c = e % LCOLS;
        int t = e / LCOLS;
        int r = t % LROWS;
        int cin = t / LROWS;
        int gh = h0 - 1 + r;
        int gw = w0 - 1 + c;
        float v = 0.0f;
        if ((unsigned)gh < (unsigned)HH && (unsigned)gw < (unsigned)WW)
            v = x[cin * (HH * WW) + gh * WW + gw];
        sm[(r * LCOLS + c) * PIX + cin] = f32_bf16(v);
    }
    const int lane = tid & 63;
    const int wave = tid >> 6;
    const int m = lane & 15;
    const int q = lane >> 4;
    const int qh = q >> 1;
    const int qc = (q & 1) * 8;
    v8s a1[3], a2[3];
    for (int kw = 0; kw < 3; ++kw) {
        for (int j = 0; j < 8; ++j) {
            a1[kw][j] = (short)f32_bf16(wgt[((m * CIN + (qc + j)) * 3 + qh) * 3 + kw]);
            short t2 = 0;
            if (q < 2)
                t2 = (short)f32_bf16(wgt[((m * CIN + (q * 8 + j)) * 3 + 2) * 3 + kw]);
            a2[kw][j] = t2;
        }
    }
    float bl[4];
    #pragma unroll
    for (int i = 0; i < 4; ++i) bl[i] = bias[q * 4 + i];
    __syncthreads();
    const int colbase = wave * 16 + m;
    for (int r = 0; r < TH; ++r) {
        v4f accA = {0.f, 0.f, 0.f, 0.f};
        v4f accB = {0.f, 0.f, 0.f, 0.f};
        #pragma unroll
        for (int kw = 0; kw < 3; ++kw) {
            const int col = colbase + kw;
            v8s b1 = *(const v8s*)&sm[((r + qh) * LCOLS + col) * PIX + qc];
            accA = __builtin_amdgcn_mfma_f32_16x16x32_bf16(a1[kw], b1, accA, 0, 0, 0);
            v8s b2 = {0, 0, 0, 0, 0, 0, 0, 0};
            if (q < 2)
                b2 = *(const v8s*)&sm[((r + 2) * LCOLS + col) * PIX + q * 8];
            accB = __builtin_amdgcn_mfma_f32_16x16x32_bf16(a2[kw], b2, accB, 0, 0, 0);
        }
        const int h = h0 + r;
        float* op = out + h * WW + (w0 + colbase);
        #pragma unroll
        for (int i = 0; i < 4; ++i)
            op[(q * 4 + i) * (HH * WW)] = accA[i] + accB[i] + bl[i];
    }
}

extern "C" void kernel_launch(void* const* d_in, const int* in_sizes, int n_in,
                              void* d_out, int out_size, void* d_ws, size_t ws_size,
                              hipStream_t stream) {
    const float* x = (const float*)d_in[0];
    const float* w = (const float*)d_in[1];
    const float* b = (const float*)d_in[2];
    float* out = (float*)d_out;
    const size_t need = (size_t)XPW * XPW * PIX * sizeof(unsigned short);  // ~33.7MB
    if (ws_size >= need) {
        unsigned short* xp = (unsigned short*)d_ws;
        conv_pack<<<dim3(XPW), dim3(256), 0, stream>>>(x, xp);
        dim3 grid(WW / TW, HH / TH);
        conv3x3_mfma<<<grid, dim3(256), 0, stream>>>(xp, w, b, out);
    } else {
        dim3 grid(WW / TW, HH / TH);
        conv3x3_mfma_fb<<<grid, dim3(256), 0, stream>>>(x, w, b, out);
    }
}

// Round 4
// 140.200 us; speedup vs baseline: 1.0644x; 1.0348x over previous
//
#include <hip/hip_runtime.h>

// Conv2D 3x3 stride-1 pad-1, C_IN=C_OUT=16, H=W=1024, fp32 in/out.
// Single fused implicit-GEMM kernel:
//  - stage 18x66 halo tile straight from fp32 NCHW: per pixel, 16 coalesced
//    dword loads (one per channel plane), RNE-pack to bf16, two ds_write_b128
//    into an XOR-swizzled [row][col][cin16] LDS layout (32B/pixel).
//  - swizzle: phys16Bchunk = c ^ ((c>>3)&1). Stride-2-chunk access patterns
//    (both the staging writes and the compute ds_read_b128) then hit all 8
//    bank-quads -> 2-way only, which is free on gfx950.
//  - compute: 5 full K=32 mfma_f32_16x16x32_bf16 per output row
//    (18 k-chunks = 9 (kh,kw) x 2 cin-halves; chunk t=4g+q on MFMA g, quad q).

#define HH 1024
#define WW 1024
#define CIN 16
#define COUT 16
#define TW 64
#define TH 16
#define LROWS (TH + 2)
#define LCOLS (TW + 2)
#define PIX 16           // shorts per pixel (32B)
#define NPIX (LROWS * LCOLS)   // 1188 pixels per tile

typedef short v8s __attribute__((ext_vector_type(8)));
typedef float v4f __attribute__((ext_vector_type(4)));
typedef unsigned int u32;

__device__ __forceinline__ unsigned short f32_bf16(float f) {
    union { float f; u32 u; } v;
    v.f = f;
    u32 u = v.u;
    u += 0x7fffu + ((u >> 16) & 1u);  // RNE
    return (unsigned short)(u >> 16);
}

__global__ __launch_bounds__(256, 4)
void conv3x3_fused(const float* __restrict__ x,
                   const float* __restrict__ wgt,
                   const float* __restrict__ bias,
                   float* __restrict__ out) {
    __shared__ __align__(16) unsigned short sm[NPIX * PIX];  // 38016 B

    const int tid = threadIdx.x;
    const int lane = tid & 63;
    const int wave = tid >> 6;
    const int h0 = blockIdx.y * TH;
    const int w0 = blockIdx.x * TW;

    // ---- stage: thread <-> pixel, 5 sweeps over 1188 pixels ----
    #pragma unroll
    for (int i = 0; i < 5; ++i) {
        const int p = i * 256 + tid;
        if (p < NPIX) {
            const int r = p / LCOLS;          // magic-mul, once per pixel
            const int col = p - r * LCOLS;
            const int gh = h0 - 1 + r;
            const int gw = w0 - 1 + col;
            float f[CIN];
            #pragma unroll
            for (int c = 0; c < CIN; ++c) f[c] = 0.0f;
            if ((unsigned)gh < (unsigned)HH && (unsigned)gw < (unsigned)WW) {
                const float* src = x + (size_t)gh * WW + gw;
                #pragma unroll
                for (int c = 0; c < CIN; ++c)
                    f[c] = src[(size_t)c * (HH * WW)];
            }
            u32 pk[8];
            #pragma unroll
            for (int c = 0; c < 8; ++c)
                pk[c] = (u32)f32_bf16(f[2 * c]) | ((u32)f32_bf16(f[2 * c + 1]) << 16);
            // pixel p -> logical chunks c0=2p (ch0..7), c0+1 (ch8..15).
            // swizzle swaps the pair iff bit3 of c0 is set.
            const int c0 = p * 2;
            const int sel = (c0 >> 3) & 1;
            uint4* dst = (uint4*)(sm + c0 * 8);   // 32B-aligned pixel slot
            dst[sel] = *(uint4*)&pk[0];
            dst[1 - sel] = *(uint4*)&pk[4];
        }
    }

    const int m = lane & 15;       // c_out row of A == pixel index n of B/D
    const int q = lane >> 4;       // quad: supplies k = 8q..8q+7 of each MFMA
    const int colbase = wave * 16 + m;

    // ---- K packing: chunk t = 4g+q, t=0..17 -> (kh,kw,half); t>=18 dead ----
    v8s a[5];
    int Kofs[5];
    #pragma unroll
    for (int g5 = 0; g5 < 5; ++g5) {
        int t = 4 * g5 + q;
        int tt = t > 17 ? 17 : t;      // dead lanes use a harmless valid addr
        int khkw = tt >> 1;
        int kh = khkw / 3;
        int kw = khkw - 3 * kh;
        int half = tt & 1;
        Kofs[g5] = (kh * LCOLS + colbase + kw) * 2 + half;
        bool valid = t < 18;
        #pragma unroll
        for (int j = 0; j < 8; ++j) {
            float wv = valid ? wgt[((m * CIN + half * 8 + j) * 3 + kh) * 3 + kw] : 0.0f;
            a[g5][j] = (short)f32_bf16(wv);
        }
    }
    float bl[4];
    #pragma unroll
    for (int i = 0; i < 4; ++i) bl[i] = bias[q * 4 + i];

    __syncthreads();

    // ---- compute: wave = 16-pixel column group, loop TH rows ----
    #pragma unroll 4
    for (int r = 0; r < TH; ++r) {
        v4f acc = {0.f, 0.f, 0.f, 0.f};
        #pragma unroll
        for (int g5 = 0; g5 < 5; ++g5) {
            int c = r * (LCOLS * 2) + Kofs[g5];  // logical chunk
            int phys = c ^ ((c >> 3) & 1);       // swizzled physical chunk
            v8s b = *(const v8s*)(sm + phys * 8);
            acc = __builtin_amdgcn_mfma_f32_16x16x32_bf16(a[g5], b, acc, 0, 0, 0);
        }
        float* op = out + (size_t)(h0 + r) * WW + (w0 + colbase);
        #pragma unroll
        for (int i = 0; i < 4; ++i)
            op[(size_t)(q * 4 + i) * (HH * WW)] = acc[i] + bl[i];
    }
}

extern "C" void kernel_launch(void* const* d_in, const int* in_sizes, int n_in,
                              void* d_out, int out_size, void* d_ws, size_t ws_size,
                              hipStream_t stream) {
    const float* x = (const float*)d_in[0];
    const float* w = (const float*)d_in[1];
    const float* b = (const float*)d_in[2];
    float* out = (float*)d_out;
    dim3 grid(WW / TW, HH / TH);
    conv3x3_fused<<<grid, dim3(256), 0, stream>>>(x, w, b, out);
}

// Round 5
// 132.125 us; speedup vs baseline: 1.1295x; 1.0611x over previous
//
#include <hip/hip_runtime.h>

// Conv2D 3x3 stride-1 pad-1, C_IN=C_OUT=16, H=W=1024, fp32 in/out.
// Fused implicit-GEMM, one kernel:
//  - staging: thread <-> (row, 4-px group). 16x global_load_dwordx4 (one per
//    channel plane, 64B/lane in flight), RNE-pack to bf16, 8x ds_write_b128.
//    66-col tile = 64-col aligned body (float4) + 2 halo cols (scalar path).
//  - LDS: [row][col][cin16], 32B/pixel, 16B-chunk XOR swizzle
//    phys = c ^ ((c>>3)&7): staging's stride-8-chunk writes cycle all 8
//    bank-quads (conflict-free) and compute's stride-2 reads stay ~2-way.
//  - compute: 5 full K=32 mfma_f32_16x16x32_bf16 per output row
//    (18 k-chunks = 9 (kh,kw) x 2 cin-halves; chunk t=4g+q on MFMA g, quad q).

#define HH 1024
#define WW 1024
#define CIN 16
#define COUT 16
#define TW 64
#define TH 16
#define LROWS (TH + 2)
#define LCOLS (TW + 2)
#define PIX 16                 // shorts per pixel (32B = 2 chunks)
#define NPIX (LROWS * LCOLS)   // 1188

typedef short v8s __attribute__((ext_vector_type(8)));
typedef float v4f __attribute__((ext_vector_type(4)));
typedef unsigned int u32;

__device__ __forceinline__ unsigned short f32_bf16(float f) {
    union { float f; u32 u; } v;
    v.f = f;
    u32 u = v.u;
    u += 0x7fffu + ((u >> 16) & 1u);  // RNE
    return (unsigned short)(u >> 16);
}

__device__ __forceinline__ int swz(int c) { return c ^ ((c >> 3) & 7); }

__global__ __launch_bounds__(256, 4)
void conv3x3_fused(const float* __restrict__ x,
                   const float* __restrict__ wgt,
                   const float* __restrict__ bias,
                   float* __restrict__ out) {
    __shared__ __align__(16) unsigned short sm[NPIX * PIX];  // 38016 B

    const int tid = threadIdx.x;
    const int lane = tid & 63;
    const int wave = tid >> 6;
    const int h0 = blockIdx.y * TH;
    const int w0 = blockIdx.x * TW;

    // ---- body staging task b (0..287): r = b>>4, 4-px group j = b&15 ----
    auto stage_body = [&](int b) {
        const int r = b >> 4;
        const int j = b & 15;
        const int gh = h0 - 1 + r;
        const int pbase = r * LCOLS + 1 + 4 * j;   // first of 4 pixels
        float4 f4[CIN];
        if ((unsigned)gh < (unsigned)HH) {
            const float4* src = (const float4*)(x + (size_t)gh * WW + w0) + j;
            #pragma unroll
            for (int c = 0; c < CIN; ++c)
                f4[c] = src[(size_t)c * (HH * WW / 4)];
        } else {
            #pragma unroll
            for (int c = 0; c < CIN; ++c)
                f4[c] = make_float4(0.f, 0.f, 0.f, 0.f);
        }
        #pragma unroll
        for (int k = 0; k < 4; ++k) {
            u32 pk[8];
            #pragma unroll
            for (int i = 0; i < 8; ++i) {
                const float lo = ((const float*)&f4[2 * i])[k];
                const float hi = ((const float*)&f4[2 * i + 1])[k];
                pk[i] = (u32)f32_bf16(lo) | ((u32)f32_bf16(hi) << 16);
            }
            #pragma unroll
            for (int half = 0; half < 2; ++half) {
                const int cc = 2 * pbase + 2 * k + half;
                *(uint4*)(sm + swz(cc) * 8) = *(uint4*)&pk[half * 4];
            }
        }
    };
    // ---- halo staging task h (0..35): r = h>>1, side = h&1 ----
    auto stage_halo = [&](int h) {
        const int r = h >> 1;
        const int side = h & 1;
        const int gh = h0 - 1 + r;
        const int gw = side ? (w0 + 64) : (w0 - 1);
        const int p = r * LCOLS + (side ? 65 : 0);
        float f[CIN];
        if ((unsigned)gh < (unsigned)HH && (unsigned)gw < (unsigned)WW) {
            const float* src = x + (size_t)gh * WW + gw;
            #pragma unroll
            for (int c = 0; c < CIN; ++c) f[c] = src[(size_t)c * (HH * WW)];
        } else {
            #pragma unroll
            for (int c = 0; c < CIN; ++c) f[c] = 0.f;
        }
        u32 pk[8];
        #pragma unroll
        for (int i = 0; i < 8; ++i)
            pk[i] = (u32)f32_bf16(f[2 * i]) | ((u32)f32_bf16(f[2 * i + 1]) << 16);
        #pragma unroll
        for (int half = 0; half < 2; ++half) {
            const int cc = 2 * p + half;
            *(uint4*)(sm + swz(cc) * 8) = *(uint4*)&pk[half * 4];
        }
    };

    stage_body(tid);                                // sweep 1: body 0..255
    if (tid < 32) stage_body(256 + tid);            // body 256..287
    else if (tid < 68) stage_halo(tid - 32);        // halo 0..35

    const int m = lane & 15;       // c_out row of A == pixel index n of B/D
    const int q = lane >> 4;       // quad: supplies k = 8q..8q+7 of each MFMA
    const int colbase = wave * 16 + m;

    // ---- K packing: chunk t = 4g+q, t=0..17 -> (kh,kw,half); t>=18 dead ----
    v8s a[5];
    int Kofs[5];
    #pragma unroll
    for (int g5 = 0; g5 < 5; ++g5) {
        int t = 4 * g5 + q;
        int tt = t > 17 ? 17 : t;      // dead lanes use a harmless valid addr
        int khkw = tt >> 1;
        int kh = khkw / 3;
        int kw = khkw - 3 * kh;
        int half = tt & 1;
        Kofs[g5] = (kh * LCOLS + colbase + kw) * 2 + half;
        bool valid = t < 18;
        #pragma unroll
        for (int j = 0; j < 8; ++j) {
            float wv = valid ? wgt[((m * CIN + half * 8 + j) * 3 + kh) * 3 + kw] : 0.0f;
            a[g5][j] = (short)f32_bf16(wv);
        }
    }
    float bl[4];
    #pragma unroll
    for (int i = 0; i < 4; ++i) bl[i] = bias[q * 4 + i];

    __syncthreads();

    // ---- compute: wave = 16-pixel column group, loop TH rows ----
    #pragma unroll 4
    for (int r = 0; r < TH; ++r) {
        v4f acc = {0.f, 0.f, 0.f, 0.f};
        #pragma unroll
        for (int g5 = 0; g5 < 5; ++g5) {
            int c = r * (LCOLS * 2) + Kofs[g5];  // logical chunk
            v8s b = *(const v8s*)(sm + swz(c) * 8);
            acc = __builtin_amdgcn_mfma_f32_16x16x32_bf16(a[g5], b, acc, 0, 0, 0);
        }
        float* op = out + (size_t)(h0 + r) * WW + (w0 + colbase);
        #pragma unroll
        for (int i = 0; i < 4; ++i)
            op[(size_t)(q * 4 + i) * (HH * WW)] = acc[i] + bl[i];
    }
}

extern "C" void kernel_launch(void* const* d_in, const int* in_sizes, int n_in,
                              void* d_out, int out_size, void* d_ws, size_t ws_size,
                              hipStream_t stream) {
    const float* x = (const float*)d_in[0];
    const float* w = (const float*)d_in[1];
    const float* b = (const float*)d_in[2];
    float* out = (float*)d_out;
    dim3 grid(WW / TW, HH / TH);
    conv3x3_fused<<<grid, dim3(256), 0, stream>>>(x, w, b, out);
}

// Round 6
// 128.624 us; speedup vs baseline: 1.1602x; 1.0272x over previous
//
#include <hip/hip_runtime.h>

// Conv2D 3x3 stride-1 pad-1, C_IN=C_OUT=16, H=W=1024, fp32 in/out.
// Fused implicit-GEMM, one kernel:
//  - weights: 2304 coalesced global loads (9/thread) -> bf16 LDS table
//    [t=0..19][m=0..15][8] (slots 18,19 zeroed); A-fragments then come from
//    5x ds_read_b128 per lane (2-way bank access = free). This removes the
//    ~40 per-lane divergent global gathers/thread that TA-serialized rounds 1-5.
//  - input staging: thread <-> (row, 4-px group). 16x global_load_dwordx4,
//    RNE-pack to bf16, 8x ds_write_b128. 66-col tile = 64-col body + 2 halo
//    cols (scalar path).
//  - LDS tile: [row][col][cin16], 32B/pixel, 16B-chunk XOR swizzle
//    phys = c ^ ((c>>3)&7).
//  - compute: 5 full K=32 mfma_f32_16x16x32_bf16 per output row
//    (18 k-chunks = 9 (kh,kw) x 2 cin-halves; chunk t=4g+q on MFMA g, quad q).

#define HH 1024
#define WW 1024
#define CIN 16
#define COUT 16
#define TW 64
#define TH 16
#define LROWS (TH + 2)
#define LCOLS (TW + 2)
#define PIX 16                 // shorts per pixel (32B = 2 chunks)
#define NPIX (LROWS * LCOLS)   // 1188

typedef short v8s __attribute__((ext_vector_type(8)));
typedef float v4f __attribute__((ext_vector_type(4)));
typedef unsigned int u32;

__device__ __forceinline__ unsigned short f32_bf16(float f) {
    union { float f; u32 u; } v;
    v.f = f;
    u32 u = v.u;
    u += 0x7fffu + ((u >> 16) & 1u);  // RNE
    return (unsigned short)(u >> 16);
}

__device__ __forceinline__ int swz(int c) { return c ^ ((c >> 3) & 7); }

__global__ __launch_bounds__(256, 3)
void conv3x3_fused(const float* __restrict__ x,
                   const float* __restrict__ wgt,
                   const float* __restrict__ bias,
                   float* __restrict__ out) {
    __shared__ __align__(16) unsigned short sm[NPIX * PIX];   // 38016 B
    __shared__ __align__(16) unsigned short wsm[20 * 16 * 8]; // 5120 B

    const int tid = threadIdx.x;
    const int lane = tid & 63;
    const int wave = tid >> 6;
    const int h0 = blockIdx.y * TH;
    const int w0 = blockIdx.x * TW;

    // ---- weights: coalesced global -> bf16 LDS table [t][m][8] ----
    // wgt linear e = m*144 + c*9 + kh*3 + kw  (c = half*8 + j)
    if (tid < 32) ((uint4*)(wsm + 18 * 16 * 8))[tid] = make_uint4(0u, 0u, 0u, 0u);
    #pragma unroll
    for (int s = 0; s < 9; ++s) {
        const int e = s * 256 + tid;   // 0..2303
        const int m = e / 144;
        const int rem = e - m * 144;
        const int c = rem / 9;
        const int r9 = rem - c * 9;    // kh*3 + kw
        const int t = r9 * 2 + (c >> 3);
        wsm[(t * 16 + m) * 8 + (c & 7)] = f32_bf16(wgt[e]);
    }

    // ---- body staging task b (0..287): r = b>>4, 4-px group j = b&15 ----
    auto stage_body = [&](int b) {
        const int r = b >> 4;
        const int j = b & 15;
        const int gh = h0 - 1 + r;
        const int pbase = r * LCOLS + 1 + 4 * j;   // first of 4 pixels
        float4 f4[CIN];
        if ((unsigned)gh < (unsigned)HH) {
            const float4* src = (const float4*)(x + (size_t)gh * WW + w0) + j;
            #pragma unroll
            for (int c = 0; c < CIN; ++c)
                f4[c] = src[(size_t)c * (HH * WW / 4)];
        } else {
            #pragma unroll
            for (int c = 0; c < CIN; ++c)
                f4[c] = make_float4(0.f, 0.f, 0.f, 0.f);
        }
        #pragma unroll
        for (int k = 0; k < 4; ++k) {
            u32 pk[8];
            #pragma unroll
            for (int i = 0; i < 8; ++i) {
                const float lo = ((const float*)&f4[2 * i])[k];
                const float hi = ((const float*)&f4[2 * i + 1])[k];
                pk[i] = (u32)f32_bf16(lo) | ((u32)f32_bf16(hi) << 16);
            }
            #pragma unroll
            for (int half = 0; half < 2; ++half) {
                const int cc = 2 * pbase + 2 * k + half;
                *(uint4*)(sm + swz(cc) * 8) = *(uint4*)&pk[half * 4];
            }
        }
    };
    // ---- halo staging task h (0..35): r = h>>1, side = h&1 ----
    auto stage_halo = [&](int h) {
        const int r = h >> 1;
        const int side = h & 1;
        const int gh = h0 - 1 + r;
        const int gw = side ? (w0 + 64) : (w0 - 1);
        const int p = r * LCOLS + (side ? 65 : 0);
        float f[CIN];
        if ((unsigned)gh < (unsigned)HH && (unsigned)gw < (unsigned)WW) {
            const float* src = x + (size_t)gh * WW + gw;
            #pragma unroll
            for (int c = 0; c < CIN; ++c) f[c] = src[(size_t)c * (HH * WW)];
        } else {
            #pragma unroll
            for (int c = 0; c < CIN; ++c) f[c] = 0.f;
        }
        u32 pk[8];
        #pragma unroll
        for (int i = 0; i < 8; ++i)
            pk[i] = (u32)f32_bf16(f[2 * i]) | ((u32)f32_bf16(f[2 * i + 1]) << 16);
        #pragma unroll
        for (int half = 0; half < 2; ++half) {
            const int cc = 2 * p + half;
            *(uint4*)(sm + swz(cc) * 8) = *(uint4*)&pk[half * 4];
        }
    };

    stage_body(tid);                                // sweep 1: body 0..255
    if (tid < 32) stage_body(256 + tid);            // body 256..287
    else if (tid < 68) stage_halo(tid - 32);        // halo 0..35

    const int m = lane & 15;       // c_out row of A == pixel index n of B/D
    const int q = lane >> 4;       // quad: supplies k = 8q..8q+7 of each MFMA
    const int colbase = wave * 16 + m;

    // ---- B-chunk offsets: chunk t = 4g+q, t<=17 -> (kh,kw,half) ----
    int Kofs[5];
    #pragma unroll
    for (int g5 = 0; g5 < 5; ++g5) {
        int t = 4 * g5 + q;
        int tt = t > 17 ? 17 : t;      // dead lanes use a harmless valid addr
        int khkw = tt >> 1;
        int kh = khkw / 3;
        int kw = khkw - 3 * kh;
        int half = tt & 1;
        Kofs[g5] = (kh * LCOLS + colbase + kw) * 2 + half;
    }
    float bl[4];
    #pragma unroll
    for (int i = 0; i < 4; ++i) bl[i] = bias[q * 4 + i];

    __syncthreads();

    // ---- A fragments from the LDS weight table (slots 18,19 are zero) ----
    v8s a[5];
    #pragma unroll
    for (int g5 = 0; g5 < 5; ++g5) {
        const int t = 4 * g5 + q;     // 0..19
        a[g5] = *(const v8s*)(wsm + (t * 16 + m) * 8);
    }

    // ---- compute: wave = 16-pixel column group, loop TH rows ----
    #pragma unroll 4
    for (int r = 0; r < TH; ++r) {
        v4f acc = {0.f, 0.f, 0.f, 0.f};
        #pragma unroll
        for (int g5 = 0; g5 < 5; ++g5) {
            int c = r * (LCOLS * 2) + Kofs[g5];  // logical chunk
            v8s b = *(const v8s*)(sm + swz(c) * 8);
            acc = __builtin_amdgcn_mfma_f32_16x16x32_bf16(a[g5], b, acc, 0, 0, 0);
        }
        float* op = out + (size_t)(h0 + r) * WW + (w0 + colbase);
        #pragma unroll
        for (int i = 0; i < 4; ++i)
            op[(size_t)(q * 4 + i) * (HH * WW)] = acc[i] + bl[i];
    }
}

extern "C" void kernel_launch(void* const* d_in, const int* in_sizes, int n_in,
                              void* d_out, int out_size, void* d_ws, size_t ws_size,
                              hipStream_t stream) {
    const float* x = (const float*)d_in[0];
    const float* w = (const float*)d_in[1];
    const float* b = (const float*)d_in[2];
    float* out = (float*)d_out;
    dim3 grid(WW / TW, HH / TH);
    conv3x3_fused<<<grid, dim3(256), 0, stream>>>(x, w, b, out);
}